// Round 11
// baseline (302.805 us; speedup 1.0000x reference)
//
#include <hip/hip_runtime.h>

// Discriminator pipeline, R11.
// R8-R10 lesson: any k1 that round-trips conv1 output (x1, 94MB) through
// global memory is latency-bound at ~45us regardless of layout/DMA tricks.
// R11 deletes the round trip: conv1 output for (one output row x 16 samples)
// is 54KB -> computed INTO LDS as swizzled MFMA B-frag slabs, consumed by
// MFMA in the same block. kprep is gone entirely.
//  kB : lc1 A-frags (bf16) + zero stats. [51 blocks]
//  k1 : block=(oh,16-samp chunk), 320 thr (5 waves):
//       A) stage image tile (5.8KB) -> conv1+lrelu -> 54 LDS slabs (54KB,
//          ds_write_b128, XOR swizzle qq^((samp>>1)&3) = 2-way-free reads)
//       B) wave w = pos (oh,ow=w): 18 MFMA from LDS (A-frags in VGPRs,
//          invalid taps = zero frag) -> y1b bf16 + BN1 stats.
//  k2 : lc2 VALU fp32, BN1 folded on bf16 uint2 loads -> y2b + BN2.
//  k3 : lc3 same -> y3b + BN3.
//  k4 : BN3 + bf16 LDS transpose -> out[8192][384] f32.

typedef float  f32x4 __attribute__((ext_vector_type(4)));
typedef float  f32x2 __attribute__((ext_vector_type(2)));
typedef short  bf16x8 __attribute__((ext_vector_type(8)));

union FR  { int4 i4; bf16x8 bf; unsigned u[4]; };

#define LRELU(v) fmaxf((v), 0.01f * (v))

static __device__ inline unsigned bfr(float f) {              // RNE fp32->bf16
    unsigned u = __float_as_uint(f);
    return (u + 0x7fffu + ((u >> 16) & 1u)) >> 16;
}
static __device__ inline unsigned short bfr16(float f) { return (unsigned short)bfr(f); }
static __device__ inline float ubf(unsigned lo16) { return __uint_as_float(lo16 << 16); }

#if __has_builtin(__builtin_elementwise_fma)
static __device__ inline f32x2 pk_fma(f32x2 a, f32x2 b, f32x2 c) { return __builtin_elementwise_fma(a, b, c); }
#else
static __device__ inline f32x2 pk_fma(f32x2 a, f32x2 b, f32x2 c) { return a * b + c; }
#endif
static __device__ inline f32x2 pk_lrelu(f32x2 v) {
#if __has_builtin(__builtin_elementwise_max)
    return __builtin_elementwise_max(v, v * 0.01f);
#else
    f32x2 r; r.x = LRELU(v.x); r.y = LRELU(v.y); return r;
#endif
}
static __device__ inline float aload(float* p) {
    return __hip_atomic_load(p, __ATOMIC_RELAXED, __HIP_MEMORY_SCOPE_AGENT);
}

// ---------------- kB: lc1 A-fragments + stats zero ----------------
__global__ __launch_bounds__(256) void kB_frags(
    const float* __restrict__ lw1,   // [16][64][450]
    int4* __restrict__ afg1, float* __restrict__ stats)
{
    const int bx = blockIdx.x, tid = threadIdx.x;
    if (bx == 50) { if (tid < 64) stats[tid] = 0.0f; return; }

    const int pos = bx;
    __shared__ float wt[9216];           // [pair=o*64+c][t]
    for (int e = tid; e < 9216; e += 256) {
        int pair = e / 9, t = e - 9 * pair;
        wt[e] = lw1[pair * 450 + pos * 9 + t];
    }
    __syncthreads();
    for (int e = tid; e < 1152; e += 256) {
        int l = e & 63, ht = e >> 6;
        int h = (ht >= 9) ? 1 : 0, t = ht - 9 * h;
        int q = l >> 4, o = l & 15;
        unsigned uu[4];
        #pragma unroll
        for (int p = 0; p < 4; ++p) {
            int c0 = 32 * h + 8 * q + 2 * p;
            float a0 = wt[(o * 64 + c0) * 9 + t];
            float a1 = wt[(o * 64 + c0 + 1) * 9 + t];
            uu[p] = bfr(a0) | (bfr(a1) << 16);
        }
        int4 st = { (int)uu[0], (int)uu[1], (int)uu[2], (int)uu[3] };
        afg1[pos * 1152 + e] = st;
    }
}

// ---------------- k1: conv1-in-LDS + lc1 MFMA, fused ----------------
__global__ __launch_bounds__(320) void k1_lc1(
    const float* __restrict__ img,   // [8192*90]
    const float* __restrict__ cw,    // conv1_w [64*4]
    const float* __restrict__ cb,    // conv1_b [64]
    const int4* __restrict__ afg,    // lc1 A-frags
    const float* __restrict__ lb,    // lc1_b [16*50]
    unsigned short* __restrict__ y1b,// bf16 [800][8192]
    float* __restrict__ stats)       // [0..31] sum16/sq16
{
    __shared__ uint4 x1L4[3456];     // 54 slab-regions x 64 uint4 = 55296 B
    __shared__ float imgP[16][110];  // 11x10 zero-padded image rows (7040 B)
    __shared__ float blL[80];        // lc1_b for 5 positions x 16 och
    __shared__ float red[32];

    const int oh = blockIdx.x % 10;
    const int chunk = blockIdx.x / 10;
    const int sb = chunk * 16;       // absolute sample base (16 samples)
    const int tid = threadIdx.x;     // 0..319

    // ---- phase A: image tile + conv1 -> LDS slabs ----
    for (int e = tid; e < 1760; e += 320) ((float*)imgP)[e] = 0.0f;
    if (tid < 80) blL[tid] = lb[(tid & 15) * 50 + oh * 5 + (tid >> 4)];
    if (tid < 32) red[tid] = 0.0f;
    __syncthreads();
    for (int e = tid; e < 1440; e += 320) {
        int s = e / 90, hw = e - s * 90;
        int r = hw / 9, c = hw - r * 9;
        imgP[s][r * 10 + c] = img[(size_t)(sb + s) * 90 + hw];
    }
    __syncthreads();

    {
        const int hq = tid & 7, h = hq >> 2, qq = hq & 3;
        const int ch0 = h * 32 + qq * 8;                 // 8 channels/thread
        f32x2 W00[4], W01[4], W10[4], W11[4], BB[4];
        #pragma unroll
        for (int p = 0; p < 4; ++p) {
            int ca = ch0 + 2 * p, cbn = ca + 1;
            W00[p] = (f32x2){cw[ca * 4 + 0], cw[cbn * 4 + 0]};
            W01[p] = (f32x2){cw[ca * 4 + 1], cw[cbn * 4 + 1]};
            W10[p] = (f32x2){cw[ca * 4 + 2], cw[cbn * 4 + 2]};
            W11[p] = (f32x2){cw[ca * 4 + 3], cw[cbn * 4 + 3]};
            BB[p]  = (f32x2){cb[ca], cb[cbn]};
        }
        // items: ((ic=3rows x 9cols)*16samp)*8(h,qq) = 3456
        for (int item = tid; item < 3456; item += 320) {
            int grp = item >> 3;                         // ic*16 + samp
            int samp = grp & 15, ic = grp >> 4;          // ic = i*9 + c
            int i = ic / 9, c = ic - 9 * i;
            int rr = min(max(oh - 1 + i, 0), 9);
            const float* ip = imgP[samp];
            float i00 = ip[rr * 10 + c],      i01 = ip[rr * 10 + c + 1];
            float i10 = ip[rr * 10 + c + 10], i11 = ip[rr * 10 + c + 11];
            unsigned u[4];
            #pragma unroll
            for (int p = 0; p < 4; ++p) {
                f32x2 v = BB[p];
                v = pk_fma((f32x2)i00, W00[p], v);
                v = pk_fma((f32x2)i01, W01[p], v);
                v = pk_fma((f32x2)i10, W10[p], v);
                v = pk_fma((f32x2)i11, W11[p], v);
                v = pk_lrelu(v);
                u[p] = bfr(v.x) | (bfr(v.y) << 16);
            }
            int qqs = qq ^ ((samp >> 1) & 3);            // bank swizzle
            x1L4[(ic * 2 + h) * 64 + samp * 4 + qqs] = make_uint4(u[0], u[1], u[2], u[3]);
        }
    }
    __syncthreads();

    // ---- phase B: per-wave MFMA for pos = (oh, ow = wave) ----
    const int w = tid >> 6;                  // 0..4
    const int lane = tid & 63;
    const int lane15 = lane & 15, q = lane >> 4;
    const int ow = w, pos = oh * 5 + ow;

    FR fa[18]; int slab[18];
    #pragma unroll
    for (int t = 0; t < 9; ++t) {
        int ti = t / 3, tj = t % 3;
        int r = oh + ti - 1, c2 = 2 * ow + tj - 1;
        bool ok = (r >= 0 && r < 10 && c2 >= 0 && c2 < 9);   // wave-uniform
        int c2c = min(max(c2, 0), 8);
        #pragma unroll
        for (int h = 0; h < 2; ++h) {
            int s = 2 * t + h;
            slab[s] = (ti * 9 + c2c) * 2 + h;
            if (ok) fa[s].i4 = afg[pos * 1152 + (h * 9 + t) * 64 + lane];
            else    fa[s].i4 = (int4){0, 0, 0, 0};
        }
    }
    const int offB = lane15 * 4 + (q ^ ((lane15 >> 1) & 3));

    f32x4 acc = (f32x4){0.f, 0.f, 0.f, 0.f};
    #pragma unroll
    for (int s = 0; s < 18; ++s) {
        FR fb; fb.i4 = ((const int4*)x1L4)[slab[s] * 64 + offB];
        acc = __builtin_amdgcn_mfma_f32_16x16x32_bf16(fa[s].bf, fb.bf, acc, 0, 0, 0);
    }

    // ---- epilogue: bias + lrelu + store + BN1 stats ----
    float so[4], sq[4];
    #pragma unroll
    for (int r = 0; r < 4; ++r) {
        int o = q * 4 + r;
        float v = acc[r] + blL[w * 16 + o];
        v = LRELU(v);
        y1b[(size_t)(o * 50 + pos) * 8192 + sb + lane15] = bfr16(v);
        so[r] = v; sq[r] = v * v;
    }
    #pragma unroll
    for (int r = 0; r < 4; ++r) {
        #pragma unroll
        for (int m = 1; m < 16; m <<= 1) {
            so[r] += __shfl_xor(so[r], m, 16);
            sq[r] += __shfl_xor(sq[r], m, 16);
        }
        if (lane15 == 0) {
            int o = q * 4 + r;
            atomicAdd(&red[o], so[r]);
            atomicAdd(&red[16 + o], sq[r]);
        }
    }
    __syncthreads();
    if (tid < 32) atomicAdd(&stats[tid], red[tid]);
}

// ---------------- k2: lc2 (VALU fp32, bf16 uint2 IO) ----------------
__global__ __launch_bounds__(256) void k2_lc2(
    const unsigned short* __restrict__ y1b,
    const float* __restrict__ lw2, const float* __restrict__ lb2,
    const float* __restrict__ g1, const float* __restrict__ be1,
    unsigned short* __restrict__ y2b, float* __restrict__ stats)
{
    __shared__ float wld[512];
    __shared__ float a1[16], b1[16], bl[8], red[16];

    const int unit = blockIdx.x;         // 528 = 66 pos x 8 chunks
    const int pos = unit >> 3, chunk = unit & 7;
    const int oh = pos / 6, ow = pos % 6;
    const int tid = threadIdx.x, lane = tid & 63;

    if (tid < 128) {
        const float* src = lw2 + tid * 264 + pos * 4;
        int o = tid >> 4, c = tid & 15;
        #pragma unroll
        for (int k = 0; k < 4; k++) wld[c * 32 + k * 8 + o] = src[k];
    }
    if (tid < 16) {
        float m = aload(&stats[tid]) * (1.0f / 409600.0f);
        float v = aload(&stats[16 + tid]) * (1.0f / 409600.0f) - m * m;
        float a = g1[tid] * rsqrtf(v + 1e-5f);
        a1[tid] = a; b1[tid] = be1[tid] - a * m;
        if (tid < 8) bl[tid] = lb2[tid * 66 + pos];
        red[tid] = 0.0f;
    }
    __syncthreads();

    int base[4]; float kmv[4];
    #pragma unroll
    for (int i = 0; i < 2; i++)
        #pragma unroll
        for (int j = 0; j < 2; j++) {
            int r = oh + i - 1, c2 = ow + j - 1;
            bool ok = (r >= 0 && r < 10 && c2 >= 0 && c2 < 5);
            int rc = min(max(r, 0), 9), cc2 = min(max(c2, 0), 4);
            base[i * 2 + j] = rc * 5 + cc2;
            kmv[i * 2 + j] = ok ? 1.0f : 0.0f;
        }

    const int sb = chunk * 1024 + tid * 4;
    float acc[8][4];
    #pragma unroll
    for (int o = 0; o < 8; o++)
        #pragma unroll
        for (int s = 0; s < 4; s++) acc[o][s] = bl[o];

    #pragma unroll 1
    for (int c = 0; c < 16; c++) {
        float av = a1[c], bv = b1[c];
        float p[4][4];
        #pragma unroll
        for (int t = 0; t < 4; t++) {
            float ap = av * kmv[t], bp = bv * kmv[t];
            uint2 U = *(const uint2*)(y1b + (size_t)(c * 50 + base[t]) * 8192 + sb);
            p[t][0] = fmaf(ap, ubf(U.x & 0xffffu), bp);
            p[t][1] = fmaf(ap, __uint_as_float(U.x & 0xffff0000u), bp);
            p[t][2] = fmaf(ap, ubf(U.y & 0xffffu), bp);
            p[t][3] = fmaf(ap, __uint_as_float(U.y & 0xffff0000u), bp);
        }
        const float4* wr = (const float4*)&wld[c * 32];
        #pragma unroll
        for (int t = 0; t < 4; t++) {
            float4 wa = wr[t * 2], wb = wr[t * 2 + 1];
            #pragma unroll
            for (int s = 0; s < 4; s++) {
                float pv = p[t][s];
                acc[0][s] += wa.x * pv; acc[1][s] += wa.y * pv;
                acc[2][s] += wa.z * pv; acc[3][s] += wa.w * pv;
                acc[4][s] += wb.x * pv; acc[5][s] += wb.y * pv;
                acc[6][s] += wb.z * pv; acc[7][s] += wb.w * pv;
            }
        }
    }

    #pragma unroll
    for (int o = 0; o < 8; o++) {
        float v0 = LRELU(acc[o][0]), v1 = LRELU(acc[o][1]);
        float v2 = LRELU(acc[o][2]), v3 = LRELU(acc[o][3]);
        uint2 st = { bfr(v0) | (bfr(v1) << 16), bfr(v2) | (bfr(v3) << 16) };
        *(uint2*)(y2b + (size_t)(o * 66 + pos) * 8192 + sb) = st;
        float sv = v0 + v1 + v2 + v3;
        float sqv = v0 * v0 + v1 * v1 + v2 * v2 + v3 * v3;
        #pragma unroll
        for (int m = 32; m > 0; m >>= 1) {
            sv  += __shfl_xor(sv, m, 64);
            sqv += __shfl_xor(sqv, m, 64);
        }
        if (lane == 0) { atomicAdd(&red[o], sv); atomicAdd(&red[8 + o], sqv); }
    }
    __syncthreads();
    if (tid < 16) atomicAdd(&stats[32 + tid], red[tid]);
}

// ---------------- k3: lc3 ----------------
__global__ __launch_bounds__(256) void k3_lc3(
    const unsigned short* __restrict__ y2b,
    const float* __restrict__ lw3, const float* __restrict__ lb3,
    const float* __restrict__ g2, const float* __restrict__ be2,
    unsigned short* __restrict__ y3b, float* __restrict__ stats)
{
    __shared__ float wld[256];
    __shared__ float a2[8], b2[8], bl[8], red[16];

    const int unit = blockIdx.x;         // 384 = 48 pos x 8 chunks
    const int pos = unit >> 3, chunk = unit & 7;
    const int oh = pos >> 2, ow = pos & 3;
    const int tid = threadIdx.x, lane = tid & 63;

    if (tid < 64) {
        const float* src = lw3 + tid * 192 + pos * 4;
        int o = tid >> 3, c = tid & 7;
        #pragma unroll
        for (int k = 0; k < 4; k++) wld[c * 32 + k * 8 + o] = src[k];
    }
    if (tid < 16) {
        if (tid < 8) {
            float m = aload(&stats[32 + tid]) * (1.0f / 540672.0f);
            float v = aload(&stats[40 + tid]) * (1.0f / 540672.0f) - m * m;
            float a = g2[tid] * rsqrtf(v + 1e-5f);
            a2[tid] = a; b2[tid] = be2[tid] - a * m;
            bl[tid] = lb3[tid * 48 + pos];
        }
        red[tid] = 0.0f;
    }
    __syncthreads();

    int base[4]; float kmv[4];
    #pragma unroll
    for (int i = 0; i < 2; i++)
        #pragma unroll
        for (int j = 0; j < 2; j++) {
            int r = oh + i - 1, c2 = 2 * ow + j - 1;
            bool ok = (r >= 0 && r < 11 && c2 >= 0 && c2 < 6);
            int rc = min(max(r, 0), 10), cc2 = min(max(c2, 0), 5);
            base[i * 2 + j] = rc * 6 + cc2;
            kmv[i * 2 + j] = ok ? 1.0f : 0.0f;
        }

    const int sb = chunk * 1024 + tid * 4;
    float acc[8][4];
    #pragma unroll
    for (int o = 0; o < 8; o++)
        #pragma unroll
        for (int s = 0; s < 4; s++) acc[o][s] = bl[o];

    #pragma unroll 1
    for (int c = 0; c < 8; c++) {
        float av = a2[c], bv = b2[c];
        float p[4][4];
        #pragma unroll
        for (int t = 0; t < 4; t++) {
            float ap = av * kmv[t], bp = bv * kmv[t];
            uint2 U = *(const uint2*)(y2b + (size_t)(c * 66 + base[t]) * 8192 + sb);
            p[t][0] = fmaf(ap, ubf(U.x & 0xffffu), bp);
            p[t][1] = fmaf(ap, __uint_as_float(U.x & 0xffff0000u), bp);
            p[t][2] = fmaf(ap, ubf(U.y & 0xffffu), bp);
            p[t][3] = fmaf(ap, __uint_as_float(U.y & 0xffff0000u), bp);
        }
        const float4* wr = (const float4*)&wld[c * 32];
        #pragma unroll
        for (int t = 0; t < 4; t++) {
            float4 wa = wr[t * 2], wb = wr[t * 2 + 1];
            #pragma unroll
            for (int s = 0; s < 4; s++) {
                float pv = p[t][s];
                acc[0][s] += wa.x * pv; acc[1][s] += wa.y * pv;
                acc[2][s] += wa.z * pv; acc[3][s] += wa.w * pv;
                acc[4][s] += wb.x * pv; acc[5][s] += wb.y * pv;
                acc[6][s] += wb.z * pv; acc[7][s] += wb.w * pv;
            }
        }
    }

    #pragma unroll
    for (int o = 0; o < 8; o++) {
        float v0 = LRELU(acc[o][0]), v1 = LRELU(acc[o][1]);
        float v2 = LRELU(acc[o][2]), v3 = LRELU(acc[o][3]);
        uint2 st = { bfr(v0) | (bfr(v1) << 16), bfr(v2) | (bfr(v3) << 16) };
        *(uint2*)(y3b + (size_t)(o * 48 + pos) * 8192 + sb) = st;
        float sv = v0 + v1 + v2 + v3;
        float sqv = v0 * v0 + v1 * v1 + v2 * v2 + v3 * v3;
        #pragma unroll
        for (int m = 32; m > 0; m >>= 1) {
            sv  += __shfl_xor(sv, m, 64);
            sqv += __shfl_xor(sqv, m, 64);
        }
        if (lane == 0) { atomicAdd(&red[o], sv); atomicAdd(&red[8 + o], sqv); }
    }
    __syncthreads();
    if (tid < 16) atomicAdd(&stats[48 + tid], red[tid]);
}

// ---------------- k4: BN3 + transpose ----------------
__global__ __launch_bounds__(256) void k4_out(
    const unsigned short* __restrict__ y3b,
    const float* __restrict__ g3, const float* __restrict__ be3,
    float* __restrict__ stats, float* __restrict__ out)
{
    __shared__ unsigned short tile[64][66];
    __shared__ float a3[8], b3[8];
    const int unit = blockIdx.x;         // 768 = 24 (6 ftiles x 4 sub) x 32 chunks
    const int tid = threadIdx.x;
    const int chunkS = unit & 31, yy = unit >> 5;
    const int ftile = yy >> 2, sub = yy & 3;
    const int fbase = ftile * 64;
    const int sbase = chunkS * 256 + sub * 64;

    if (tid < 8) {
        float m = aload(&stats[48 + tid]) * (1.0f / 393216.0f);
        float v = aload(&stats[56 + tid]) * (1.0f / 393216.0f) - m * m;
        float a = g3[tid] * rsqrtf(v + 1e-5f);
        a3[tid] = a; b3[tid] = be3[tid] - a * m;
    }
    __syncthreads();

    #pragma unroll
    for (int rep = 0; rep < 16; rep++) {
        int idx = rep * 256 + tid;
        int f = idx >> 6, s = idx & 63;
        tile[f][s] = y3b[(size_t)(fbase + f) * 8192 + sbase + s];
    }
    __syncthreads();
    #pragma unroll
    for (int rep = 0; rep < 16; rep++) {
        int idx = rep * 256 + tid;
        int s = idx >> 6, f = idx & 63;
        int ff = fbase + f;
        int o = ff / 48;
        float x = ubf((unsigned)tile[f][s]);
        out[(size_t)(sbase + s) * 384 + ff] = a3[o] * x + b3[o];
    }
}

extern "C" void kernel_launch(void* const* d_in, const int* in_sizes, int n_in,
                              void* d_out, int out_size, void* d_ws, size_t ws_size,
                              hipStream_t stream) {
    const float* image   = (const float*)d_in[0];
    const float* conv1_w = (const float*)d_in[1];
    const float* conv1_b = (const float*)d_in[2];
    const float* lc1_w   = (const float*)d_in[3];
    const float* lc1_b   = (const float*)d_in[4];
    const float* lc2_w   = (const float*)d_in[5];
    const float* lc2_b   = (const float*)d_in[6];
    const float* lc3_w   = (const float*)d_in[7];
    const float* lc3_b   = (const float*)d_in[8];
    const float* gamma1  = (const float*)d_in[9];
    const float* beta1   = (const float*)d_in[10];
    const float* gamma2  = (const float*)d_in[11];
    const float* beta2   = (const float*)d_in[12];
    const float* gamma3  = (const float*)d_in[13];
    const float* beta3   = (const float*)d_in[14];
    float* outp = (float*)d_out;

    char* wsb = (char*)d_ws;
    float*          stats = (float*)wsb;                       // 1024 B
    unsigned short* y1b   = (unsigned short*)(wsb + 1024);     // 13,107,200 B
    unsigned short* y2b   = (unsigned short*)(wsb + 13108224); // 8,650,752 B
    unsigned short* y3b   = (unsigned short*)(wsb + 21758976); // 6,291,456 B
    int4*           afg1  = (int4*)(wsb + 28050432);           // 921,600 B

    kB_frags<<<dim3(51),   dim3(256), 0, stream>>>(lc1_w, afg1, stats);
    k1_lc1  <<<dim3(5120), dim3(320), 0, stream>>>(image, conv1_w, conv1_b,
                                                   afg1, lc1_b, y1b, stats);
    k2_lc2  <<<dim3(528),  dim3(256), 0, stream>>>(y1b, lc2_w, lc2_b,
                                                   gamma1, beta1, y2b, stats);
    k3_lc3  <<<dim3(384),  dim3(256), 0, stream>>>(y2b, lc3_w, lc3_b,
                                                   gamma2, beta2, y3b, stats);
    k4_out  <<<dim3(768),  dim3(256), 0, stream>>>(y3b, gamma3, beta3, stats, outp);
}